// Round 5
// baseline (245.407 us; speedup 1.0000x reference)
//
#include <hip/hip_runtime.h>
#include <hip/hip_bf16.h>

#define SDIM 48
#define SP   110592           // 48^3
#define C_IN 16
#define O_OUT 32
#define T27  27
#define G81  81

typedef __attribute__((ext_vector_type(8))) short bf16x8;
typedef __attribute__((ext_vector_type(4))) float f32x4;
typedef __attribute__((ext_vector_type(2))) float f32x2;

__device__ __forceinline__ float bf2f(unsigned short u) {
    unsigned int x = ((unsigned int)u) << 16;
    return __builtin_bit_cast(float, x);
}
__device__ __forceinline__ unsigned short f2bf(float f) {
    unsigned int x = __builtin_bit_cast(unsigned int, f);
    x += 0x7fffu + ((x >> 16) & 1u);     // RNE
    return (unsigned short)(x >> 16);
}

// ---------- Kernel 0a: x [n][c][sp] fp32 -> xT [n][sp][c] bf16 ---------------
__global__ __launch_bounds__(256)
void prep_xT(const float* __restrict__ x, unsigned short* __restrict__ xT) {
    __shared__ float l[256 * 17];
    const int tid = threadIdx.x;
    const int b   = blockIdx.x;          // 0..863
    const int n   = b / 432;
    const int sp0 = (b - n * 432) * 256;
    #pragma unroll
    for (int c = 0; c < 16; ++c)
        l[tid * 17 + c] = x[((size_t)(n * 16 + c)) * SP + sp0 + tid];
    __syncthreads();
    unsigned int u[8];
    #pragma unroll
    for (int q = 0; q < 8; ++q) {
        unsigned short a = f2bf(l[tid * 17 + 2 * q]);
        unsigned short bb = f2bf(l[tid * 17 + 2 * q + 1]);
        u[q] = (unsigned int)a | ((unsigned int)bb << 16);
    }
    uint4* dst = (uint4*)(xT + ((size_t)(n * SP + sp0 + tid)) * 16);
    dst[0] = make_uint4(u[0], u[1], u[2], u[3]);
    dst[1] = make_uint4(u[4], u[5], u[6], u[7]);
}

// ---------- Kernel 0b: pack offset-conv weights into B-fragment layout -------
__global__ __launch_bounds__(256)
void prep_bfrag(const float* __restrict__ ow, unsigned short* __restrict__ Bf) {
    int idx = blockIdx.x * 256 + threadIdx.x;     // 0..43007
    int r    = idx & 7;
    int lane = (idx >> 3) & 63;
    int snt  = idx >> 9;                          // s*6+nt, 0..83
    int s = snt / 6, nt = snt - s * 6;
    int kk  = ((lane >> 4) << 3) + r;
    int g   = nt * 16 + (lane & 15);
    int tap = 2 * s + (kk >> 4);
    int c   = kk & 15;
    float v = 0.f;
    if (tap < 27 && g < 81) v = ow[((size_t)(g * 16 + c)) * 27 + tap];
    Bf[idx] = f2bf(v);
}

// ---------- Kernel 0c: pack einsum weights [32][16][27] into B-frag layout ---
__global__ __launch_bounds__(256)
void prep_wfrag(const float* __restrict__ w, unsigned short* __restrict__ Wf) {
    int idx = blockIdx.x * 256 + threadIdx.x;     // 0..14335
    int r    = idx & 7;
    int lane = (idx >> 3) & 63;
    int snt  = idx >> 9;                          // s*2+nt, 0..27
    int s = snt >> 1, nt = snt & 1;
    int kk  = ((lane >> 4) << 3) + r;
    int o   = nt * 16 + (lane & 15);
    int tap = 2 * s + (kk >> 4);
    int c   = kk & 15;
    float v = 0.f;
    if (tap < 27) v = w[((size_t)(o * 16 + c)) * 27 + tap];
    Wf[idx] = f2bf(v);
}

// ---------- Kernel 1: offset conv as implicit-GEMM MFMA ----------------------
__global__ __launch_bounds__(256)
void offs_conv_mfma(const unsigned short* __restrict__ xT,
                    const unsigned short* __restrict__ Bf,
                    const float* __restrict__ ob,
                    unsigned short* __restrict__ offs) {
    __shared__ unsigned short Alds[256 * 8];      // 4KB
    const int tid  = threadIdx.x;
    const int lane = tid & 63;
    const int wid  = tid >> 6;
    const int j    = wid;
    const int m    = tid & 63;
    const int gm   = blockIdx.x * 64 + m;
    const int n    = (gm >= SP) ? 1 : 0;
    const int sp   = gm - n * SP;
    const int z    = sp / 2304;
    const int rem  = sp - z * 2304;
    const int y    = rem / 48;
    const int xx   = rem - y * 48;
    const int tapoff = j >> 1;
    const int half   = j & 1;

    auto stage_load = [&](int s) -> uint4 {
        int tap = 2 * s + tapoff;
        int kd = tap / 9;
        int t2 = tap - kd * 9;
        int kh = t2 / 3;
        int kw = t2 - kh * 3;
        int di = z + kd - 1, hi = y + kh - 1, wi = xx + kw - 1;
        bool ok = (tap < 27) && ((unsigned)di < 48u) && ((unsigned)hi < 48u) &&
                  ((unsigned)wi < 48u);
        uint4 v = make_uint4(0u, 0u, 0u, 0u);
        if (ok) {
            size_t off = ((size_t)(n * SP + (di * 2304 + hi * 48 + wi))) * 16 + half * 8;
            v = *(const uint4*)(xT + off);
        }
        return v;
    };

    f32x4 acc[6];
    #pragma unroll
    for (int t = 0; t < 6; ++t) acc[t] = (f32x4){0.f, 0.f, 0.f, 0.f};

    uint4 v = stage_load(0);
    for (int s = 0; s < 14; ++s) {
        __syncthreads();
        *(uint4*)&Alds[tid * 8] = v;
        __syncthreads();
        if (s < 13) v = stage_load(s + 1);        // prefetch overlaps MFMA
        bf16x8 a = *(const bf16x8*)&Alds[(((lane >> 4) * 64) + (wid * 16) + (lane & 15)) * 8];
        const bf16x8* bp = (const bf16x8*)Bf + (size_t)(s * 6) * 64 + lane;
        #pragma unroll
        for (int nt = 0; nt < 6; ++nt) {
            bf16x8 b = bp[nt * 64];
            acc[nt] = __builtin_amdgcn_mfma_f32_16x16x32_bf16(a, b, acc[nt], 0, 0, 0);
        }
    }

    const int mrow = wid * 16 + ((lane >> 4) << 2);
    const int gmr  = blockIdx.x * 64 + mrow;
    const int n2   = (gmr >= SP) ? 1 : 0;
    const int spr  = gmr - n2 * SP;
    #pragma unroll
    for (int nt = 0; nt < 6; ++nt) {
        int g = nt * 16 + (lane & 15);
        if (g < 81) {
            float bia = ob[g];
            unsigned short h0 = f2bf(acc[nt][0] + bia);
            unsigned short h1 = f2bf(acc[nt][1] + bia);
            unsigned short h2 = f2bf(acc[nt][2] + bia);
            unsigned short h3 = f2bf(acc[nt][3] + bia);
            uint2 pv;
            pv.x = (unsigned int)h0 | ((unsigned int)h1 << 16);
            pv.y = (unsigned int)h2 | ((unsigned int)h3 << 16);
            *(uint2*)(offs + ((size_t)(n2 * 81 + g)) * SP + spr) = pv;
        }
    }
}

// ---------- Kernel 2: fused trilinear sampling + MFMA einsum -----------------
// One tap per thread per round: 4 taps x 64 points per LDS round, K=64/round
// (2 MFMA k-steps), 7 rounds = 28 taps (tap 27 zero). Double-buffered LDS,
// conflict-free [tapslot][chhalf][point][16B] layout, 1 barrier/round.
__global__ __launch_bounds__(256, 8)
void deform_mfma(const unsigned short* __restrict__ xT,
                 const unsigned short* __restrict__ Wf,
                 const unsigned short* __restrict__ offs,
                 float* __restrict__ out) {
    __shared__ __align__(16) unsigned char smem[16384];   // 2 x 8KB A-tile bufs
    unsigned short* Abuf = (unsigned short*)smem;         // [b][tap][chh][pt][8]
    float*          olds = (float*)smem;                  // epilogue alias

    const int tid  = threadIdx.x;
    const int lane = tid & 63;
    const int wid  = tid >> 6;                    // tap slot 0..3
    const int m    = lane;                        // point within tile
    const int n    = (blockIdx.x >= 1728) ? 1 : 0;
    const int sp0  = blockIdx.x * 64 - n * SP;
    const int sp   = sp0 + m;
    const int z    = sp / 2304;
    const int rm   = sp - z * 2304;
    const int y    = rm / 48;
    const int xx   = rm - y * 48;

    const unsigned short* offn = offs + (size_t)n * G81 * SP + sp;
    const uint4* xq4 = (const uint4*)(xT + (size_t)n * SP * 16);

    struct Stg { uint4 a, b; };

    auto stage = [&](int rr) -> Stg {
        Stg res;
        res.a = make_uint4(0u, 0u, 0u, 0u);
        res.b = make_uint4(0u, 0u, 0u, 0u);
        const int tap = 4 * rr + wid;
        if (tap >= 27) return res;
        const int kd = tap / 9;
        const int t2 = tap - kd * 9;
        const int kh = t2 / 3;
        const int kw = t2 - kh * 3;
        float pd = (float)(z + kd - 1)  + bf2f(offn[(size_t)tap * SP]);
        float ph = (float)(y + kh - 1)  + bf2f(offn[(size_t)(27 + tap) * SP]);
        float pw = (float)(xx + kw - 1) + bf2f(offn[(size_t)(54 + tap) * SP]);
        float df = floorf(pd), hf = floorf(ph), wf = floorf(pw);
        float fd = pd - df, fh = ph - hf, fw = pw - wf;
        int d0 = (int)df, h0 = (int)hf, w0 = (int)wf;
        float wd0 = ((unsigned)d0       < 48u) ? (1.f - fd) : 0.f;
        float wd1 = ((unsigned)(d0 + 1) < 48u) ? fd : 0.f;
        float wh0 = ((unsigned)h0       < 48u) ? (1.f - fh) : 0.f;
        float wh1 = ((unsigned)(h0 + 1) < 48u) ? fh : 0.f;
        float ww0 = ((unsigned)w0       < 48u) ? (1.f - fw) : 0.f;
        float ww1 = ((unsigned)(w0 + 1) < 48u) ? fw : 0.f;
        int dc0 = min(max(d0,     0), 47) * 2304;
        int dc1 = min(max(d0 + 1, 0), 47) * 2304;
        int hc0 = min(max(h0,     0), 47) * 48;
        int hc1 = min(max(h0 + 1, 0), 47) * 48;
        int wc0 = min(max(w0,     0), 47);
        int wc1 = min(max(w0 + 1, 0), 47);

        float wdh[4] = {wd0 * wh0, wd0 * wh1, wd1 * wh0, wd1 * wh1};
        int   rdh[4] = {dc0 + hc0, dc0 + hc1, dc1 + hc0, dc1 + hc1};

        f32x2 s2v[8];
        #pragma unroll
        for (int q = 0; q < 8; ++q) s2v[q] = (f32x2){0.f, 0.f};

        #pragma unroll
        for (int g2 = 0; g2 < 2; ++g2) {          // 4 corners per batch
            uint4 cv[8];
            float cwt[4];
            #pragma unroll
            for (int pidx = 0; pidx < 2; ++pidx) {
                int jj = g2 * 2 + pidx;           // dh combo
                int i0 = rdh[jj] + wc0;
                int i1 = rdh[jj] + wc1;
                cv[pidx * 4 + 0] = xq4[(size_t)i0 * 2];
                cv[pidx * 4 + 1] = xq4[(size_t)i0 * 2 + 1];
                cv[pidx * 4 + 2] = xq4[(size_t)i1 * 2];
                cv[pidx * 4 + 3] = xq4[(size_t)i1 * 2 + 1];
                cwt[pidx * 2 + 0] = wdh[jj] * ww0;
                cwt[pidx * 2 + 1] = wdh[jj] * ww1;
            }
            #pragma unroll
            for (int pidx = 0; pidx < 2; ++pidx) {
                #pragma unroll
                for (int wsel = 0; wsel < 2; ++wsel) {
                    f32x2 w2;
                    w2.x = cwt[pidx * 2 + wsel];
                    w2.y = w2.x;
                    const uint4& lo4 = cv[pidx * 4 + wsel * 2];
                    const uint4& hi4 = cv[pidx * 4 + wsel * 2 + 1];
                    unsigned int wd_[8] = {lo4.x, lo4.y, lo4.z, lo4.w,
                                           hi4.x, hi4.y, hi4.z, hi4.w};
                    #pragma unroll
                    for (int q = 0; q < 8; ++q) {
                        f32x2 xv;
                        xv.x = __builtin_bit_cast(float, wd_[q] << 16);
                        xv.y = __builtin_bit_cast(float, wd_[q] & 0xffff0000u);
                        s2v[q] = __builtin_elementwise_fma(xv, w2, s2v[q]);
                    }
                }
            }
        }
        unsigned int o_[8];
        #pragma unroll
        for (int q = 0; q < 8; ++q) {
            unsigned int r_;
            asm("v_cvt_pk_bf16_f32 %0, %1, %2" : "=v"(r_) : "v"(s2v[q].x), "v"(s2v[q].y));
            o_[q] = r_;
        }
        res.a = make_uint4(o_[0], o_[1], o_[2], o_[3]);
        res.b = make_uint4(o_[4], o_[5], o_[6], o_[7]);
        return res;
    };

    // LDS indexers: [buf][tapslot][chh][point][8 ush]
    auto aoff = [](int b, int ts, int ch, int pt) -> int {
        return (((b * 4 + ts) * 2 + ch) * 64 + pt) * 8;
    };

    f32x4 acc0 = (f32x4){0.f, 0.f, 0.f, 0.f};
    f32x4 acc1 = (f32x4){0.f, 0.f, 0.f, 0.f};

    const int q_   = lane >> 4;
    const int tl   = q_ >> 1;                     // tap-local within k-step
    const int chh  = q_ & 1;                      // channel half
    const int rowm = wid * 16 + (lane & 15);      // A-fragment row (point)

    Stg v = stage(0);
    *(uint4*)&Abuf[aoff(0, wid, 0, m)] = v.a;
    *(uint4*)&Abuf[aoff(0, wid, 1, m)] = v.b;
    __syncthreads();

    int cur = 0;
    for (int rr = 0; rr < 7; ++rr) {
        if (rr < 6) v = stage(rr + 1);            // gathers overlap MFMA below
        bf16x8 a0 = *(const bf16x8*)&Abuf[aoff(cur, tl,     chh, rowm)];
        bf16x8 a1 = *(const bf16x8*)&Abuf[aoff(cur, 2 + tl, chh, rowm)];
        const bf16x8* bp0 = (const bf16x8*)Wf + (size_t)((2 * rr + 0) * 2) * 64 + lane;
        const bf16x8* bp1 = (const bf16x8*)Wf + (size_t)((2 * rr + 1) * 2) * 64 + lane;
        acc0 = __builtin_amdgcn_mfma_f32_16x16x32_bf16(a0, bp0[0],  acc0, 0, 0, 0);
        acc1 = __builtin_amdgcn_mfma_f32_16x16x32_bf16(a0, bp0[64], acc1, 0, 0, 0);
        acc0 = __builtin_amdgcn_mfma_f32_16x16x32_bf16(a1, bp1[0],  acc0, 0, 0, 0);
        acc1 = __builtin_amdgcn_mfma_f32_16x16x32_bf16(a1, bp1[64], acc1, 0, 0, 0);
        if (rr < 6) {
            *(uint4*)&Abuf[aoff(cur ^ 1, wid, 0, m)] = v.a;
            *(uint4*)&Abuf[aoff(cur ^ 1, wid, 1, m)] = v.b;
        }
        __syncthreads();
        cur ^= 1;
    }

    // epilogue: transpose through LDS (aliased) -> coalesced float4 stores
    const int mr = wid * 16 + ((lane >> 4) << 2);
    {
        int o = lane & 15;
        #pragma unroll
        for (int r = 0; r < 4; ++r) olds[o * 65 + mr + r] = acc0[r];
        #pragma unroll
        for (int r = 0; r < 4; ++r) olds[(16 + o) * 65 + mr + r] = acc1[r];
    }
    __syncthreads();
    const int o  = tid >> 3;
    const int m8 = (tid & 7) * 8;
    float* op = out + ((size_t)(n * O_OUT + o)) * SP + sp0 + m8;
    float4 a0s = make_float4(olds[o * 65 + m8],     olds[o * 65 + m8 + 1],
                             olds[o * 65 + m8 + 2], olds[o * 65 + m8 + 3]);
    float4 a1s = make_float4(olds[o * 65 + m8 + 4], olds[o * 65 + m8 + 5],
                             olds[o * 65 + m8 + 6], olds[o * 65 + m8 + 7]);
    *(float4*)op       = a0s;
    *(float4*)(op + 4) = a1s;
}

// -----------------------------------------------------------------------------
extern "C" void kernel_launch(void* const* d_in, const int* in_sizes, int n_in,
                              void* d_out, int out_size, void* d_ws, size_t ws_size,
                              hipStream_t stream) {
    (void)in_sizes; (void)n_in; (void)out_size; (void)ws_size;
    const float* x      = (const float*)d_in[0];
    const float* weight = (const float*)d_in[1];
    const float* ow     = (const float*)d_in[2];
    const float* ob     = (const float*)d_in[3];
    float* out = (float*)d_out;

    unsigned short* offs_b = (unsigned short*)d_ws;            // 2*81*SP bf16 = 35.8MB
    unsigned short* xT     = offs_b + (size_t)2 * 81 * SP;     // 2*SP*16 bf16 = 7.1MB
    unsigned short* Bf     = xT + (size_t)2 * SP * 16;         // 43008 bf16
    unsigned short* Wf     = Bf + 43008;                       // 14336 bf16

    prep_xT<<<864, 256, 0, stream>>>(x, xT);
    prep_bfrag<<<168, 256, 0, stream>>>(ow, Bf);
    prep_wfrag<<<56, 256, 0, stream>>>(weight, Wf);
    offs_conv_mfma<<<3456, 256, 0, stream>>>(xT, Bf, ob, offs_b);
    deform_mfma<<<3456, 256, 0, stream>>>(xT, Wf, offs_b, out);
}

// Round 6
// 171.930 us; speedup vs baseline: 1.4274x; 1.4274x over previous
//
#include <hip/hip_runtime.h>
#include <hip/hip_bf16.h>

#define SDIM 48
#define SP   110592           // 48^3
#define C_IN 16
#define O_OUT 32
#define T27  27
#define G81  81

typedef __attribute__((ext_vector_type(8))) short bf16x8;
typedef __attribute__((ext_vector_type(4))) float f32x4;
typedef __attribute__((ext_vector_type(2))) float f32x2;

__device__ __forceinline__ float bf2f(unsigned short u) {
    unsigned int x = ((unsigned int)u) << 16;
    return __builtin_bit_cast(float, x);
}
__device__ __forceinline__ unsigned short f2bf(float f) {
    unsigned int x = __builtin_bit_cast(unsigned int, f);
    x += 0x7fffu + ((x >> 16) & 1u);     // RNE
    return (unsigned short)(x >> 16);
}

// ---------- Kernel 0a: x [n][c][sp] fp32 -> xT [n][sp][c] bf16 ---------------
__global__ __launch_bounds__(256)
void prep_xT(const float* __restrict__ x, unsigned short* __restrict__ xT) {
    __shared__ float l[256 * 17];
    const int tid = threadIdx.x;
    const int b   = blockIdx.x;          // 0..863
    const int n   = b / 432;
    const int sp0 = (b - n * 432) * 256;
    #pragma unroll
    for (int c = 0; c < 16; ++c)
        l[tid * 17 + c] = x[((size_t)(n * 16 + c)) * SP + sp0 + tid];
    __syncthreads();
    unsigned int u[8];
    #pragma unroll
    for (int q = 0; q < 8; ++q) {
        unsigned short a = f2bf(l[tid * 17 + 2 * q]);
        unsigned short bb = f2bf(l[tid * 17 + 2 * q + 1]);
        u[q] = (unsigned int)a | ((unsigned int)bb << 16);
    }
    uint4* dst = (uint4*)(xT + ((size_t)(n * SP + sp0 + tid)) * 16);
    dst[0] = make_uint4(u[0], u[1], u[2], u[3]);
    dst[1] = make_uint4(u[4], u[5], u[6], u[7]);
}

// ---------- Kernel 0b: pack offset-conv weights into B-fragment layout -------
__global__ __launch_bounds__(256)
void prep_bfrag(const float* __restrict__ ow, unsigned short* __restrict__ Bf) {
    int idx = blockIdx.x * 256 + threadIdx.x;     // 0..43007
    int r    = idx & 7;
    int lane = (idx >> 3) & 63;
    int snt  = idx >> 9;                          // s*6+nt, 0..83
    int s = snt / 6, nt = snt - s * 6;
    int kk  = ((lane >> 4) << 3) + r;
    int g   = nt * 16 + (lane & 15);
    int tap = 2 * s + (kk >> 4);
    int c   = kk & 15;
    float v = 0.f;
    if (tap < 27 && g < 81) v = ow[((size_t)(g * 16 + c)) * 27 + tap];
    Bf[idx] = f2bf(v);
}

// ---------- Kernel 0c: pack einsum weights [32][16][27] into B-frag layout ---
__global__ __launch_bounds__(256)
void prep_wfrag(const float* __restrict__ w, unsigned short* __restrict__ Wf) {
    int idx = blockIdx.x * 256 + threadIdx.x;     // 0..14335
    int r    = idx & 7;
    int lane = (idx >> 3) & 63;
    int snt  = idx >> 9;                          // s*2+nt, 0..27
    int s = snt >> 1, nt = snt & 1;
    int kk  = ((lane >> 4) << 3) + r;
    int o   = nt * 16 + (lane & 15);
    int tap = 2 * s + (kk >> 4);
    int c   = kk & 15;
    float v = 0.f;
    if (tap < 27) v = w[((size_t)(o * 16 + c)) * 27 + tap];
    Wf[idx] = f2bf(v);
}

// ---------- Kernel 1: offset conv as implicit-GEMM MFMA ----------------------
__global__ __launch_bounds__(256)
void offs_conv_mfma(const unsigned short* __restrict__ xT,
                    const unsigned short* __restrict__ Bf,
                    const float* __restrict__ ob,
                    unsigned short* __restrict__ offs) {
    __shared__ unsigned short Alds[256 * 8];      // 4KB
    const int tid  = threadIdx.x;
    const int lane = tid & 63;
    const int wid  = tid >> 6;
    const int j    = wid;
    const int m    = tid & 63;
    const int gm   = blockIdx.x * 64 + m;
    const int n    = (gm >= SP) ? 1 : 0;
    const int sp   = gm - n * SP;
    const int z    = sp / 2304;
    const int rem  = sp - z * 2304;
    const int y    = rem / 48;
    const int xx   = rem - y * 48;
    const int tapoff = j >> 1;
    const int half   = j & 1;

    auto stage_load = [&](int s) -> uint4 {
        int tap = 2 * s + tapoff;
        int kd = tap / 9;
        int t2 = tap - kd * 9;
        int kh = t2 / 3;
        int kw = t2 - kh * 3;
        int di = z + kd - 1, hi = y + kh - 1, wi = xx + kw - 1;
        bool ok = (tap < 27) && ((unsigned)di < 48u) && ((unsigned)hi < 48u) &&
                  ((unsigned)wi < 48u);
        uint4 v = make_uint4(0u, 0u, 0u, 0u);
        if (ok) {
            size_t off = ((size_t)(n * SP + (di * 2304 + hi * 48 + wi))) * 16 + half * 8;
            v = *(const uint4*)(xT + off);
        }
        return v;
    };

    f32x4 acc[6];
    #pragma unroll
    for (int t = 0; t < 6; ++t) acc[t] = (f32x4){0.f, 0.f, 0.f, 0.f};

    uint4 v = stage_load(0);
    for (int s = 0; s < 14; ++s) {
        __syncthreads();
        *(uint4*)&Alds[tid * 8] = v;
        __syncthreads();
        if (s < 13) v = stage_load(s + 1);        // prefetch overlaps MFMA
        bf16x8 a = *(const bf16x8*)&Alds[(((lane >> 4) * 64) + (wid * 16) + (lane & 15)) * 8];
        const bf16x8* bp = (const bf16x8*)Bf + (size_t)(s * 6) * 64 + lane;
        #pragma unroll
        for (int nt = 0; nt < 6; ++nt) {
            bf16x8 b = bp[nt * 64];
            acc[nt] = __builtin_amdgcn_mfma_f32_16x16x32_bf16(a, b, acc[nt], 0, 0, 0);
        }
    }

    const int mrow = wid * 16 + ((lane >> 4) << 2);
    const int gmr  = blockIdx.x * 64 + mrow;
    const int n2   = (gmr >= SP) ? 1 : 0;
    const int spr  = gmr - n2 * SP;
    #pragma unroll
    for (int nt = 0; nt < 6; ++nt) {
        int g = nt * 16 + (lane & 15);
        if (g < 81) {
            float bia = ob[g];
            unsigned short h0 = f2bf(acc[nt][0] + bia);
            unsigned short h1 = f2bf(acc[nt][1] + bia);
            unsigned short h2 = f2bf(acc[nt][2] + bia);
            unsigned short h3 = f2bf(acc[nt][3] + bia);
            uint2 pv;
            pv.x = (unsigned int)h0 | ((unsigned int)h1 << 16);
            pv.y = (unsigned int)h2 | ((unsigned int)h3 << 16);
            *(uint2*)(offs + ((size_t)(n2 * 81 + g)) * SP + spr) = pv;
        }
    }
}

// ---------- Kernel 2: fused trilinear sampling + MFMA einsum -----------------
// One tap per thread per round: 4 taps x 64 points per LDS round, K=64/round
// (2 MFMA k-steps), 7 rounds = 28 taps (tap 27 zero). Double-buffered LDS,
// conflict-free [tapslot][chhalf][point][16B] layout, 1 barrier/round.
// NOTE: launch_bounds min-waves MUST stay at 4 — (256,8) caps VGPR at 32 and
// spills stage()'s ~56-reg working set to scratch (R5: FETCH 45->322MB).
__global__ __launch_bounds__(256, 4)
void deform_mfma(const unsigned short* __restrict__ xT,
                 const unsigned short* __restrict__ Wf,
                 const unsigned short* __restrict__ offs,
                 float* __restrict__ out) {
    __shared__ __align__(16) unsigned char smem[16384];   // 2 x 8KB A-tile bufs
    unsigned short* Abuf = (unsigned short*)smem;         // [b][tap][chh][pt][8]
    float*          olds = (float*)smem;                  // epilogue alias

    const int tid  = threadIdx.x;
    const int lane = tid & 63;
    const int wid  = tid >> 6;                    // tap slot 0..3
    const int m    = lane;                        // point within tile
    const int n    = (blockIdx.x >= 1728) ? 1 : 0;
    const int sp0  = blockIdx.x * 64 - n * SP;
    const int sp   = sp0 + m;
    const int z    = sp / 2304;
    const int rm   = sp - z * 2304;
    const int y    = rm / 48;
    const int xx   = rm - y * 48;

    const unsigned short* offn = offs + (size_t)n * G81 * SP + sp;
    const uint4* xq4 = (const uint4*)(xT + (size_t)n * SP * 16);

    struct Stg { uint4 a, b; };

    auto stage = [&](int rr) -> Stg {
        Stg res;
        res.a = make_uint4(0u, 0u, 0u, 0u);
        res.b = make_uint4(0u, 0u, 0u, 0u);
        const int tap = 4 * rr + wid;
        if (tap >= 27) return res;
        const int kd = tap / 9;
        const int t2 = tap - kd * 9;
        const int kh = t2 / 3;
        const int kw = t2 - kh * 3;
        float pd = (float)(z + kd - 1)  + bf2f(offn[(size_t)tap * SP]);
        float ph = (float)(y + kh - 1)  + bf2f(offn[(size_t)(27 + tap) * SP]);
        float pw = (float)(xx + kw - 1) + bf2f(offn[(size_t)(54 + tap) * SP]);
        float df = floorf(pd), hf = floorf(ph), wf = floorf(pw);
        float fd = pd - df, fh = ph - hf, fw = pw - wf;
        int d0 = (int)df, h0 = (int)hf, w0 = (int)wf;
        float wd0 = ((unsigned)d0       < 48u) ? (1.f - fd) : 0.f;
        float wd1 = ((unsigned)(d0 + 1) < 48u) ? fd : 0.f;
        float wh0 = ((unsigned)h0       < 48u) ? (1.f - fh) : 0.f;
        float wh1 = ((unsigned)(h0 + 1) < 48u) ? fh : 0.f;
        float ww0 = ((unsigned)w0       < 48u) ? (1.f - fw) : 0.f;
        float ww1 = ((unsigned)(w0 + 1) < 48u) ? fw : 0.f;
        int dc0 = min(max(d0,     0), 47) * 2304;
        int dc1 = min(max(d0 + 1, 0), 47) * 2304;
        int hc0 = min(max(h0,     0), 47) * 48;
        int hc1 = min(max(h0 + 1, 0), 47) * 48;
        int wc0 = min(max(w0,     0), 47);
        int wc1 = min(max(w0 + 1, 0), 47);

        float wdh[4] = {wd0 * wh0, wd0 * wh1, wd1 * wh0, wd1 * wh1};
        int   rdh[4] = {dc0 + hc0, dc0 + hc1, dc1 + hc0, dc1 + hc1};

        f32x2 s2v[8];
        #pragma unroll
        for (int q = 0; q < 8; ++q) s2v[q] = (f32x2){0.f, 0.f};

        #pragma unroll
        for (int g2 = 0; g2 < 2; ++g2) {          // 4 corners per batch
            uint4 cv[8];
            float cwt[4];
            #pragma unroll
            for (int pidx = 0; pidx < 2; ++pidx) {
                int jj = g2 * 2 + pidx;           // dh combo
                int i0 = rdh[jj] + wc0;
                int i1 = rdh[jj] + wc1;
                cv[pidx * 4 + 0] = xq4[(size_t)i0 * 2];
                cv[pidx * 4 + 1] = xq4[(size_t)i0 * 2 + 1];
                cv[pidx * 4 + 2] = xq4[(size_t)i1 * 2];
                cv[pidx * 4 + 3] = xq4[(size_t)i1 * 2 + 1];
                cwt[pidx * 2 + 0] = wdh[jj] * ww0;
                cwt[pidx * 2 + 1] = wdh[jj] * ww1;
            }
            #pragma unroll
            for (int pidx = 0; pidx < 2; ++pidx) {
                #pragma unroll
                for (int wsel = 0; wsel < 2; ++wsel) {
                    f32x2 w2;
                    w2.x = cwt[pidx * 2 + wsel];
                    w2.y = w2.x;
                    const uint4& lo4 = cv[pidx * 4 + wsel * 2];
                    const uint4& hi4 = cv[pidx * 4 + wsel * 2 + 1];
                    unsigned int wd_[8] = {lo4.x, lo4.y, lo4.z, lo4.w,
                                           hi4.x, hi4.y, hi4.z, hi4.w};
                    #pragma unroll
                    for (int q = 0; q < 8; ++q) {
                        f32x2 xv;
                        xv.x = __builtin_bit_cast(float, wd_[q] << 16);
                        xv.y = __builtin_bit_cast(float, wd_[q] & 0xffff0000u);
                        s2v[q] = __builtin_elementwise_fma(xv, w2, s2v[q]);
                    }
                }
            }
        }
        unsigned int o_[8];
        #pragma unroll
        for (int q = 0; q < 8; ++q) {
            unsigned int r_;
            asm("v_cvt_pk_bf16_f32 %0, %1, %2" : "=v"(r_) : "v"(s2v[q].x), "v"(s2v[q].y));
            o_[q] = r_;
        }
        res.a = make_uint4(o_[0], o_[1], o_[2], o_[3]);
        res.b = make_uint4(o_[4], o_[5], o_[6], o_[7]);
        return res;
    };

    // LDS indexers: [buf][tapslot][chh][point][8 ush]
    auto aoff = [](int b, int ts, int ch, int pt) -> int {
        return (((b * 4 + ts) * 2 + ch) * 64 + pt) * 8;
    };

    f32x4 acc0 = (f32x4){0.f, 0.f, 0.f, 0.f};
    f32x4 acc1 = (f32x4){0.f, 0.f, 0.f, 0.f};

    const int q_   = lane >> 4;
    const int tl   = q_ >> 1;                     // tap-local within k-step
    const int chh  = q_ & 1;                      // channel half
    const int rowm = wid * 16 + (lane & 15);      // A-fragment row (point)

    Stg v = stage(0);
    *(uint4*)&Abuf[aoff(0, wid, 0, m)] = v.a;
    *(uint4*)&Abuf[aoff(0, wid, 1, m)] = v.b;
    __syncthreads();

    int cur = 0;
    for (int rr = 0; rr < 7; ++rr) {
        if (rr < 6) v = stage(rr + 1);            // gathers overlap MFMA below
        bf16x8 a0 = *(const bf16x8*)&Abuf[aoff(cur, tl,     chh, rowm)];
        bf16x8 a1 = *(const bf16x8*)&Abuf[aoff(cur, 2 + tl, chh, rowm)];
        const bf16x8* bp0 = (const bf16x8*)Wf + (size_t)((2 * rr + 0) * 2) * 64 + lane;
        const bf16x8* bp1 = (const bf16x8*)Wf + (size_t)((2 * rr + 1) * 2) * 64 + lane;
        acc0 = __builtin_amdgcn_mfma_f32_16x16x32_bf16(a0, bp0[0],  acc0, 0, 0, 0);
        acc1 = __builtin_amdgcn_mfma_f32_16x16x32_bf16(a0, bp0[64], acc1, 0, 0, 0);
        acc0 = __builtin_amdgcn_mfma_f32_16x16x32_bf16(a1, bp1[0],  acc0, 0, 0, 0);
        acc1 = __builtin_amdgcn_mfma_f32_16x16x32_bf16(a1, bp1[64], acc1, 0, 0, 0);
        if (rr < 6) {
            *(uint4*)&Abuf[aoff(cur ^ 1, wid, 0, m)] = v.a;
            *(uint4*)&Abuf[aoff(cur ^ 1, wid, 1, m)] = v.b;
        }
        __syncthreads();
        cur ^= 1;
    }

    // epilogue: transpose through LDS (aliased) -> coalesced float4 stores
    const int mr = wid * 16 + ((lane >> 4) << 2);
    {
        int o = lane & 15;
        #pragma unroll
        for (int r = 0; r < 4; ++r) olds[o * 65 + mr + r] = acc0[r];
        #pragma unroll
        for (int r = 0; r < 4; ++r) olds[(16 + o) * 65 + mr + r] = acc1[r];
    }
    __syncthreads();
    const int o  = tid >> 3;
    const int m8 = (tid & 7) * 8;
    float* op = out + ((size_t)(n * O_OUT + o)) * SP + sp0 + m8;
    float4 a0s = make_float4(olds[o * 65 + m8],     olds[o * 65 + m8 + 1],
                             olds[o * 65 + m8 + 2], olds[o * 65 + m8 + 3]);
    float4 a1s = make_float4(olds[o * 65 + m8 + 4], olds[o * 65 + m8 + 5],
                             olds[o * 65 + m8 + 6], olds[o * 65 + m8 + 7]);
    *(float4*)op       = a0s;
    *(float4*)(op + 4) = a1s;
}

// -----------------------------------------------------------------------------
extern "C" void kernel_launch(void* const* d_in, const int* in_sizes, int n_in,
                              void* d_out, int out_size, void* d_ws, size_t ws_size,
                              hipStream_t stream) {
    (void)in_sizes; (void)n_in; (void)out_size; (void)ws_size;
    const float* x      = (const float*)d_in[0];
    const float* weight = (const float*)d_in[1];
    const float* ow     = (const float*)d_in[2];
    const float* ob     = (const float*)d_in[3];
    float* out = (float*)d_out;

    unsigned short* offs_b = (unsigned short*)d_ws;            // 2*81*SP bf16 = 35.8MB
    unsigned short* xT     = offs_b + (size_t)2 * 81 * SP;     // 2*SP*16 bf16 = 7.1MB
    unsigned short* Bf     = xT + (size_t)2 * SP * 16;         // 43008 bf16
    unsigned short* Wf     = Bf + 43008;                       // 14336 bf16

    prep_xT<<<864, 256, 0, stream>>>(x, xT);
    prep_bfrag<<<168, 256, 0, stream>>>(ow, Bf);
    prep_wfrag<<<56, 256, 0, stream>>>(weight, Wf);
    offs_conv_mfma<<<3456, 256, 0, stream>>>(xT, Bf, ob, offs_b);
    deform_mfma<<<3456, 256, 0, stream>>>(xT, Wf, offs_b, out);
}

// Round 7
// 169.970 us; speedup vs baseline: 1.4438x; 1.0115x over previous
//
#include <hip/hip_runtime.h>
#include <hip/hip_bf16.h>

#define SDIM 48
#define SP   110592           // 48^3
#define C_IN 16
#define O_OUT 32
#define T27  27
#define G81  81

typedef __attribute__((ext_vector_type(8))) short bf16x8;
typedef __attribute__((ext_vector_type(4))) float f32x4;
typedef __attribute__((ext_vector_type(2))) float f32x2;

__device__ __forceinline__ float bf2f(unsigned short u) {
    unsigned int x = ((unsigned int)u) << 16;
    return __builtin_bit_cast(float, x);
}
__device__ __forceinline__ unsigned short f2bf(float f) {
    unsigned int x = __builtin_bit_cast(unsigned int, f);
    x += 0x7fffu + ((x >> 16) & 1u);     // RNE
    return (unsigned short)(x >> 16);
}

// ---------- Kernel 0a: x [n][c][sp] fp32 -> xT [n][sp][c] bf16 ---------------
__global__ __launch_bounds__(256)
void prep_xT(const float* __restrict__ x, unsigned short* __restrict__ xT) {
    __shared__ float l[256 * 17];
    const int tid = threadIdx.x;
    const int b   = blockIdx.x;          // 0..863
    const int n   = b / 432;
    const int sp0 = (b - n * 432) * 256;
    #pragma unroll
    for (int c = 0; c < 16; ++c)
        l[tid * 17 + c] = x[((size_t)(n * 16 + c)) * SP + sp0 + tid];
    __syncthreads();
    unsigned int u[8];
    #pragma unroll
    for (int q = 0; q < 8; ++q) {
        unsigned short a = f2bf(l[tid * 17 + 2 * q]);
        unsigned short bb = f2bf(l[tid * 17 + 2 * q + 1]);
        u[q] = (unsigned int)a | ((unsigned int)bb << 16);
    }
    uint4* dst = (uint4*)(xT + ((size_t)(n * SP + sp0 + tid)) * 16);
    dst[0] = make_uint4(u[0], u[1], u[2], u[3]);
    dst[1] = make_uint4(u[4], u[5], u[6], u[7]);
}

// ---------- Kernel 0b: pack offset-conv weights into B-fragment layout -------
__global__ __launch_bounds__(256)
void prep_bfrag(const float* __restrict__ ow, unsigned short* __restrict__ Bf) {
    int idx = blockIdx.x * 256 + threadIdx.x;     // 0..43007
    int r    = idx & 7;
    int lane = (idx >> 3) & 63;
    int snt  = idx >> 9;                          // s*6+nt, 0..83
    int s = snt / 6, nt = snt - s * 6;
    int kk  = ((lane >> 4) << 3) + r;
    int g   = nt * 16 + (lane & 15);
    int tap = 2 * s + (kk >> 4);
    int c   = kk & 15;
    float v = 0.f;
    if (tap < 27 && g < 81) v = ow[((size_t)(g * 16 + c)) * 27 + tap];
    Bf[idx] = f2bf(v);
}

// ---------- Kernel 0c: pack einsum weights [32][16][27] into B-frag layout ---
__global__ __launch_bounds__(256)
void prep_wfrag(const float* __restrict__ w, unsigned short* __restrict__ Wf) {
    int idx = blockIdx.x * 256 + threadIdx.x;     // 0..14335
    int r    = idx & 7;
    int lane = (idx >> 3) & 63;
    int snt  = idx >> 9;                          // s*2+nt, 0..27
    int s = snt >> 1, nt = snt & 1;
    int kk  = ((lane >> 4) << 3) + r;
    int o   = nt * 16 + (lane & 15);
    int tap = 2 * s + (kk >> 4);
    int c   = kk & 15;
    float v = 0.f;
    if (tap < 27) v = w[((size_t)(o * 16 + c)) * 27 + tap];
    Wf[idx] = f2bf(v);
}

// ---------- Kernel 1: offset conv as implicit-GEMM MFMA ----------------------
__global__ __launch_bounds__(256)
void offs_conv_mfma(const unsigned short* __restrict__ xT,
                    const unsigned short* __restrict__ Bf,
                    const float* __restrict__ ob,
                    unsigned short* __restrict__ offs) {
    __shared__ unsigned short Alds[256 * 8];      // 4KB
    const int tid  = threadIdx.x;
    const int lane = tid & 63;
    const int wid  = tid >> 6;
    const int j    = wid;
    const int m    = tid & 63;
    const int gm   = blockIdx.x * 64 + m;
    const int n    = (gm >= SP) ? 1 : 0;
    const int sp   = gm - n * SP;
    const int z    = sp / 2304;
    const int rem  = sp - z * 2304;
    const int y    = rem / 48;
    const int xx   = rem - y * 48;
    const int tapoff = j >> 1;
    const int half   = j & 1;

    auto stage_load = [&](int s) -> uint4 {
        int tap = 2 * s + tapoff;
        int kd = tap / 9;
        int t2 = tap - kd * 9;
        int kh = t2 / 3;
        int kw = t2 - kh * 3;
        int di = z + kd - 1, hi = y + kh - 1, wi = xx + kw - 1;
        bool ok = (tap < 27) && ((unsigned)di < 48u) && ((unsigned)hi < 48u) &&
                  ((unsigned)wi < 48u);
        uint4 v = make_uint4(0u, 0u, 0u, 0u);
        if (ok) {
            size_t off = ((size_t)(n * SP + (di * 2304 + hi * 48 + wi))) * 16 + half * 8;
            v = *(const uint4*)(xT + off);
        }
        return v;
    };

    f32x4 acc[6];
    #pragma unroll
    for (int t = 0; t < 6; ++t) acc[t] = (f32x4){0.f, 0.f, 0.f, 0.f};

    uint4 v = stage_load(0);
    for (int s = 0; s < 14; ++s) {
        __syncthreads();
        *(uint4*)&Alds[tid * 8] = v;
        __syncthreads();
        if (s < 13) v = stage_load(s + 1);        // prefetch overlaps MFMA
        bf16x8 a = *(const bf16x8*)&Alds[(((lane >> 4) * 64) + (wid * 16) + (lane & 15)) * 8];
        const bf16x8* bp = (const bf16x8*)Bf + (size_t)(s * 6) * 64 + lane;
        #pragma unroll
        for (int nt = 0; nt < 6; ++nt) {
            bf16x8 b = bp[nt * 64];
            acc[nt] = __builtin_amdgcn_mfma_f32_16x16x32_bf16(a, b, acc[nt], 0, 0, 0);
        }
    }

    const int mrow = wid * 16 + ((lane >> 4) << 2);
    const int gmr  = blockIdx.x * 64 + mrow;
    const int n2   = (gmr >= SP) ? 1 : 0;
    const int spr  = gmr - n2 * SP;
    #pragma unroll
    for (int nt = 0; nt < 6; ++nt) {
        int g = nt * 16 + (lane & 15);
        if (g < 81) {
            float bia = ob[g];
            unsigned short h0 = f2bf(acc[nt][0] + bia);
            unsigned short h1 = f2bf(acc[nt][1] + bia);
            unsigned short h2 = f2bf(acc[nt][2] + bia);
            unsigned short h3 = f2bf(acc[nt][3] + bia);
            uint2 pv;
            pv.x = (unsigned int)h0 | ((unsigned int)h1 << 16);
            pv.y = (unsigned int)h2 | ((unsigned int)h3 << 16);
            *(uint2*)(offs + ((size_t)(n2 * 81 + g)) * SP + spr) = pv;
        }
    }
}

// ---------- Kernel 2: fused sampling + MFMA, single-phase per block ----------
// Block = 448 threads = 16 points x 28 taps, ONE (point,tap) sample/thread.
// All offset loads + gathers issue in parallel (one latency chain per block,
// was 7 serial rounds). Then: 1 barrier, M=16 GEMM with K=448 split 2 k-steps
// per wave (7 waves x 4 MFMA), partial-C fp32 reduce through LDS.
// VGPR cap 512/7=73 > the 64 that held this sampling body at 60 regs (R5/R6);
// if FETCH_SIZE explodes vs ~45MB it means spill — revisit.
__global__ __launch_bounds__(448, 7)
void deform_fused(const unsigned short* __restrict__ xT,
                  const unsigned short* __restrict__ Wf,
                  const unsigned short* __restrict__ offs,
                  float* __restrict__ out) {
    // staging: S[16 pts][488 ush] (976B rows: start-bank step 20 -> spread)
    // alias:   Cpart[7 waves][32 o][20 f] for partial-C reduction
    __shared__ __align__(16) unsigned char smem[17920];
    unsigned short* S  = (unsigned short*)smem;
    float*          Cp = (float*)smem;

    const int tid  = threadIdx.x;
    const int lane = tid & 63;
    const int wv   = tid >> 6;                    // wave 0..6
    const int p    = tid & 15;                    // point in tile
    const int t    = tid >> 4;                    // tap 0..27
    const int n    = (blockIdx.x >= 6912) ? 1 : 0;
    const int sp0  = blockIdx.x * 16 - n * SP;
    const int sp   = sp0 + p;
    const int z    = sp / 2304;
    const int rm   = sp - z * 2304;
    const int y    = rm / 48;
    const int xx   = rm - y * 48;

    const unsigned short* offn = offs + (size_t)n * G81 * SP + sp;
    const uint4* xq4 = (const uint4*)(xT + (size_t)n * SP * 16);

    // ---- phase 1: sample (p, t) -> 16 bf16 channels ----
    uint4 ra = make_uint4(0u, 0u, 0u, 0u);
    uint4 rb = make_uint4(0u, 0u, 0u, 0u);
    if (t < 27) {
        const int kd = t / 9;
        const int t2 = t - kd * 9;
        const int kh = t2 / 3;
        const int kw = t2 - kh * 3;
        float pd = (float)(z + kd - 1)  + bf2f(offn[(size_t)t * SP]);
        float ph = (float)(y + kh - 1)  + bf2f(offn[(size_t)(27 + t) * SP]);
        float pw = (float)(xx + kw - 1) + bf2f(offn[(size_t)(54 + t) * SP]);
        float df = floorf(pd), hf = floorf(ph), wf = floorf(pw);
        float fd = pd - df, fh = ph - hf, fw = pw - wf;
        int d0 = (int)df, h0 = (int)hf, w0 = (int)wf;
        float wd0 = ((unsigned)d0       < 48u) ? (1.f - fd) : 0.f;
        float wd1 = ((unsigned)(d0 + 1) < 48u) ? fd : 0.f;
        float wh0 = ((unsigned)h0       < 48u) ? (1.f - fh) : 0.f;
        float wh1 = ((unsigned)(h0 + 1) < 48u) ? fh : 0.f;
        float ww0 = ((unsigned)w0       < 48u) ? (1.f - fw) : 0.f;
        float ww1 = ((unsigned)(w0 + 1) < 48u) ? fw : 0.f;
        int dc0 = min(max(d0,     0), 47) * 2304;
        int dc1 = min(max(d0 + 1, 0), 47) * 2304;
        int hc0 = min(max(h0,     0), 47) * 48;
        int hc1 = min(max(h0 + 1, 0), 47) * 48;
        int wc0 = min(max(w0,     0), 47);
        int wc1 = min(max(w0 + 1, 0), 47);

        float wdh[4] = {wd0 * wh0, wd0 * wh1, wd1 * wh0, wd1 * wh1};
        int   rdh[4] = {dc0 + hc0, dc0 + hc1, dc1 + hc0, dc1 + hc1};

        f32x2 s2v[8];
        #pragma unroll
        for (int q = 0; q < 8; ++q) s2v[q] = (f32x2){0.f, 0.f};

        #pragma unroll
        for (int g2 = 0; g2 < 2; ++g2) {          // 4 corners per batch
            uint4 cv[8];
            float cwt[4];
            #pragma unroll
            for (int pidx = 0; pidx < 2; ++pidx) {
                int jj = g2 * 2 + pidx;           // dh combo
                int i0 = rdh[jj] + wc0;
                int i1 = rdh[jj] + wc1;
                cv[pidx * 4 + 0] = xq4[(size_t)i0 * 2];
                cv[pidx * 4 + 1] = xq4[(size_t)i0 * 2 + 1];
                cv[pidx * 4 + 2] = xq4[(size_t)i1 * 2];
                cv[pidx * 4 + 3] = xq4[(size_t)i1 * 2 + 1];
                cwt[pidx * 2 + 0] = wdh[jj] * ww0;
                cwt[pidx * 2 + 1] = wdh[jj] * ww1;
            }
            #pragma unroll
            for (int pidx = 0; pidx < 2; ++pidx) {
                #pragma unroll
                for (int wsel = 0; wsel < 2; ++wsel) {
                    f32x2 w2;
                    w2.x = cwt[pidx * 2 + wsel];
                    w2.y = w2.x;
                    const uint4& lo4 = cv[pidx * 4 + wsel * 2];
                    const uint4& hi4 = cv[pidx * 4 + wsel * 2 + 1];
                    unsigned int wd_[8] = {lo4.x, lo4.y, lo4.z, lo4.w,
                                           hi4.x, hi4.y, hi4.z, hi4.w};
                    #pragma unroll
                    for (int q = 0; q < 8; ++q) {
                        f32x2 xv;
                        xv.x = __builtin_bit_cast(float, wd_[q] << 16);
                        xv.y = __builtin_bit_cast(float, wd_[q] & 0xffff0000u);
                        s2v[q] = __builtin_elementwise_fma(xv, w2, s2v[q]);
                    }
                }
            }
        }
        unsigned int o_[8];
        #pragma unroll
        for (int q = 0; q < 8; ++q) {
            unsigned int r_;
            asm("v_cvt_pk_bf16_f32 %0, %1, %2" : "=v"(r_) : "v"(s2v[q].x), "v"(s2v[q].y));
            o_[q] = r_;
        }
        ra = make_uint4(o_[0], o_[1], o_[2], o_[3]);
        rb = make_uint4(o_[4], o_[5], o_[6], o_[7]);
    }
    // staging store: S[p][t*16 .. t*16+15] (t=27 writes zeros)
    {
        unsigned short* wp_ = S + p * 488 + t * 16;
        *(uint4*)wp_       = ra;
        *(uint4*)(wp_ + 8) = rb;
    }
    __syncthreads();

    // ---- phase 2: GEMM M=16, N=32, K=448; wave wv owns k-steps 2wv, 2wv+1 ---
    f32x4 acc0 = (f32x4){0.f, 0.f, 0.f, 0.f};
    f32x4 acc1 = (f32x4){0.f, 0.f, 0.f, 0.f};
    {
        const int q   = lane >> 4;
        const int pr  = lane & 15;
        const int ks0 = 2 * wv;
        bf16x8 a0 = *(const bf16x8*)(S + pr * 488 + ks0 * 32 + q * 8);
        bf16x8 a1 = *(const bf16x8*)(S + pr * 488 + (ks0 + 1) * 32 + q * 8);
        const bf16x8* bp0 = (const bf16x8*)Wf + (size_t)((ks0 + 0) * 2) * 64 + lane;
        const bf16x8* bp1 = (const bf16x8*)Wf + (size_t)((ks0 + 1) * 2) * 64 + lane;
        acc0 = __builtin_amdgcn_mfma_f32_16x16x32_bf16(a0, bp0[0],  acc0, 0, 0, 0);
        acc1 = __builtin_amdgcn_mfma_f32_16x16x32_bf16(a0, bp0[64], acc1, 0, 0, 0);
        acc0 = __builtin_amdgcn_mfma_f32_16x16x32_bf16(a1, bp1[0],  acc0, 0, 0, 0);
        acc1 = __builtin_amdgcn_mfma_f32_16x16x32_bf16(a1, bp1[64], acc1, 0, 0, 0);
    }
    __syncthreads();   // staging reads done -> safe to overwrite with Cpart

    // ---- phase 3: partial-C write + fp32 reduce + store ----
    {
        const int o16 = lane & 15;
        const int m0  = (lane >> 4) << 2;
        *(f32x4*)&Cp[(wv * 32 + o16)      * 20 + m0] = acc0;
        *(f32x4*)&Cp[(wv * 32 + 16 + o16) * 20 + m0] = acc1;
    }
    __syncthreads();

    #pragma unroll
    for (int rep = 0; rep < 2; ++rep) {
        int idx = tid + rep * 448;
        if (rep == 0 || tid < 64) {
            int o = idx >> 4;
            int m = idx & 15;
            float r0 = 0.f;
            #pragma unroll
            for (int w2 = 0; w2 < 7; ++w2)
                r0 += Cp[(w2 * 32 + o) * 20 + m];
            out[((size_t)(n * O_OUT + o)) * SP + sp0 + m] = r0;
        }
    }
}

// -----------------------------------------------------------------------------
extern "C" void kernel_launch(void* const* d_in, const int* in_sizes, int n_in,
                              void* d_out, int out_size, void* d_ws, size_t ws_size,
                              hipStream_t stream) {
    (void)in_sizes; (void)n_in; (void)out_size; (void)ws_size;
    const float* x      = (const float*)d_in[0];
    const float* weight = (const float*)d_in[1];
    const float* ow     = (const float*)d_in[2];
    const float* ob     = (const float*)d_in[3];
    float* out = (float*)d_out;

    unsigned short* offs_b = (unsigned short*)d_ws;            // 2*81*SP bf16 = 35.8MB
    unsigned short* xT     = offs_b + (size_t)2 * 81 * SP;     // 2*SP*16 bf16 = 7.1MB
    unsigned short* Bf     = xT + (size_t)2 * SP * 16;         // 43008 bf16
    unsigned short* Wf     = Bf + 43008;                       // 14336 bf16

    prep_xT<<<864, 256, 0, stream>>>(x, xT);
    prep_bfrag<<<168, 256, 0, stream>>>(ow, Bf);
    prep_wfrag<<<56, 256, 0, stream>>>(weight, Wf);
    offs_conv_mfma<<<3456, 256, 0, stream>>>(xT, Bf, ob, offs_b);
    deform_fused<<<13824, 448, 0, stream>>>(xT, Wf, offs_b, out);
}